// Round 17
// baseline (424.779 us; speedup 1.0000x reference)
//
#include <hip/hip_runtime.h>

#define DIM 384
#define SPD 32768   // 32*32*32 spatial per batch

using short8v = __attribute__((ext_vector_type(8))) short;
using f32x4   = __attribute__((ext_vector_type(4))) float;
using int4v   = __attribute__((ext_vector_type(4))) int;
using int2v   = __attribute__((ext_vector_type(2))) int;

__device__ __forceinline__ float b2f(short s) {
  unsigned u = ((unsigned)(unsigned short)s) << 16;
  return __builtin_bit_cast(float, u);
}
__device__ __forceinline__ short f2b(float f) {
  unsigned u = __builtin_bit_cast(unsigned, f);
  u += 0x7FFFu + ((u >> 16) & 1u);   // RNE
  return (short)(u >> 16);
}
__device__ __forceinline__ unsigned char f2fp8(float f) {
  return (unsigned char)(__builtin_amdgcn_cvt_pk_fp8_f32(f, f, 0, false) & 0xff);
}
// pack 4 floats -> 4 fp8 bytes (byte0 = a)
__device__ __forceinline__ int pk4_fp8(float a, float b, float c, float d) {
  int r = 0;
  r = __builtin_amdgcn_cvt_pk_fp8_f32(a, b, r, false);
  r = __builtin_amdgcn_cvt_pk_fp8_f32(c, d, r, true);
  return r;
}
// tanh-form GELU as x*sigmoid(x*(c1 + c2*x^2)); max |err| vs erf-GELU ~3e-4
__device__ __forceinline__ float fast_gelu(float v) {
  float v2 = v * v;
  float wn = v * __builtin_fmaf(-0.0713548162f, v2, -1.5957691216f);
  float e = __expf(wn);
  return v * __builtin_amdgcn_rcpf(1.0f + e);
}

// ---------------- K0: weights fp32 (K,N) -> transposed; qkv/fc1/fc2 -> fp8,
// proj -> bf16 ----------------
__global__ __launch_bounds__(256) void wprep(
    const float* __restrict__ qkv_w, const float* __restrict__ proj_w,
    const float* __restrict__ fc1_w, const float* __restrict__ fc2_w,
    unsigned char* __restrict__ qkvT8, short* __restrict__ projT,
    unsigned char* __restrict__ fc1T8, unsigned char* __restrict__ fc2T8) {
  int blk = blockIdx.x;
  const float* src; short* dst = nullptr; unsigned char* dst8 = nullptr; int K, N;
  if (blk < 432)       {              src = qkv_w;  dst8 = qkvT8; K = 384;  N = 1152; }
  else if (blk < 576)  { blk -= 432;  src = proj_w; dst = projT;  K = 384;  N = 384;  }
  else if (blk < 1152) { blk -= 576;  src = fc1_w;  dst8 = fc1T8; K = 384;  N = 1536; }
  else                 { blk -= 1152; src = fc2_w;  dst8 = fc2T8; K = 1536; N = 384;  }
  int tn = N >> 5;
  int k0 = (blk / tn) << 5, n0 = (blk % tn) << 5;
  __shared__ float tile[32][33];
  int lr = threadIdx.x >> 5, lc = threadIdx.x & 31;
#pragma unroll
  for (int i = 0; i < 4; ++i) {
    int r = i * 8 + lr;
    tile[r][lc] = src[(size_t)(k0 + r) * N + n0 + lc];
  }
  __syncthreads();
#pragma unroll
  for (int i = 0; i < 4; ++i) {
    int r = i * 8 + lr;
    if (dst) dst[(size_t)(n0 + r) * K + k0 + lc] = f2b(tile[lc][r]);
    else     dst8[(size_t)(n0 + r) * K + k0 + lc] = f2fp8(tile[lc][r]);
  }
}

// ---------------- K1: LN1 + (B,C,D,H,W) -> token-major FP8 ----------------
__global__ __launch_bounds__(256) void ln1_part(
    const float* __restrict__ x, const float* __restrict__ g,
    const float* __restrict__ b, unsigned char* __restrict__ xln) {
  __shared__ float tile[32 * 385];   // [s][c], padded row stride
  __shared__ float sg[DIM], sb[DIM];
  int tid = threadIdx.x;
  int t0 = blockIdx.x << 5;
  int bb = t0 >> 15, s0 = t0 & (SPD - 1);
  const float* xb = x + ((size_t)bb * DIM) * SPD + s0;
  for (int i = tid; i < DIM; i += 256) { sg[i] = g[i]; sb[i] = b[i]; }
  for (int i = tid; i < DIM * 32; i += 256) {
    int c = i >> 5, sl = i & 31;
    tile[sl * 385 + c] = xb[(size_t)c * SPD + sl];
  }
  __syncthreads();
  int sl = tid >> 3, j = tid & 7;   // 8 lanes per token
  const float* row = &tile[sl * 385];
  float sum = 0.f, sq = 0.f;
#pragma unroll
  for (int u = 0; u < 48; ++u) { float v = row[j * 48 + u]; sum += v; sq += v * v; }
#pragma unroll
  for (int off = 1; off < 8; off <<= 1) { sum += __shfl_xor(sum, off); sq += __shfl_xor(sq, off); }
  float mean = sum * (1.f / 384.f);
  float rstd = rsqrtf(sq * (1.f / 384.f) - mean * mean + 1e-5f);
  unsigned char* orow = xln + (size_t)(t0 + sl) * DIM + j * 48;
#pragma unroll
  for (int c8 = 0; c8 < 48; c8 += 8) {
    float f[8];
#pragma unroll
    for (int u = 0; u < 8; ++u) {
      int c = j * 48 + c8 + u;
      f[u] = (row[c] - mean) * rstd * sg[c] + sb[c];
    }
    int2v o = { pk4_fp8(f[0], f[1], f[2], f[3]), pk4_fp8(f[4], f[5], f[6], f[7]) };
    *(int2v*)(orow + c8) = o;
  }
}

// ---------------- proj GEMM (bf16, r0-exact): C = aout @ projT^T --------------
__global__ __launch_bounds__(256, 3) void gemm_proj(
    const short* __restrict__ A, const short* __restrict__ BT,
    const float* __restrict__ bias, const float* __restrict__ res,
    float* __restrict__ O, int K, int N, int bnCnt) {
  __shared__ char smem[33792];
  int tid = threadIdx.x;
  int nwg = gridDim.x;
  int cpx = nwg >> 3;
  int swz = ((int)blockIdx.x & 7) * cpx + ((int)blockIdx.x >> 3);
  int bm = swz / bnCnt, bn = swz - bm * bnCnt;
  size_t t0 = (size_t)bm * 128;
  const short* Ab = A + (t0 + (tid >> 2)) * K + ((tid & 3) * 8);
  const short* Bb = BT + ((size_t)bn * 128 + (tid >> 2)) * K + ((tid & 3) * 8);
  f32x4 acc[4][4];
#pragma unroll
  for (int i = 0; i < 4; ++i)
#pragma unroll
    for (int j = 0; j < 4; ++j) acc[i][j] = (f32x4){0.f, 0.f, 0.f, 0.f};
  int w = tid >> 6, l = tid & 63;
  int wm = w >> 1, wn = w & 1, lr = l & 15, lk = l >> 4;

  auto stage = [&](int buf, int kt) {
    char* base = smem + buf * 16384;
    __builtin_amdgcn_global_load_lds((const void*)(Ab + kt), (void*)(base + tid * 16), 16, 0, 0);
    __builtin_amdgcn_global_load_lds((const void*)(Ab + kt + (size_t)64 * K), (void*)(base + 4096 + tid * 16), 16, 0, 0);
    __builtin_amdgcn_global_load_lds((const void*)(Bb + kt), (void*)(base + 8192 + tid * 16), 16, 0, 0);
    __builtin_amdgcn_global_load_lds((const void*)(Bb + kt + (size_t)64 * K), (void*)(base + 12288 + tid * 16), 16, 0, 0);
  };
  auto compute = [&](int buf) {
    short* bA = (short*)smem + buf * 8192 + (wm * 64 + lr) * 32 + lk * 8;
    short* bB = (short*)smem + buf * 8192 + 4096 + (wn * 64 + lr) * 32 + lk * 8;
    short8v af[4], bfr[4];
#pragma unroll
    for (int mi = 0; mi < 4; ++mi) af[mi] = *(short8v*)(bA + mi * 16 * 32);
#pragma unroll
    for (int ni = 0; ni < 4; ++ni) bfr[ni] = *(short8v*)(bB + ni * 16 * 32);
#pragma unroll
    for (int mi = 0; mi < 4; ++mi)
#pragma unroll
      for (int ni = 0; ni < 4; ++ni)
        acc[mi][ni] = __builtin_amdgcn_mfma_f32_16x16x32_bf16(af[mi], bfr[ni], acc[mi][ni], 0, 0, 0);
  };

  int nt = K >> 5;
  stage(0, 0);
  __syncthreads();
  for (int t = 1; t < nt; ++t) {
    stage(t & 1, t * 32);
    compute((t - 1) & 1);
    __syncthreads();
  }
  compute((nt - 1) & 1);

  float bs[4];
#pragma unroll
  for (int ni = 0; ni < 4; ++ni) bs[ni] = bias[bn * 128 + wn * 64 + ni * 16 + lr];

  __syncthreads();
  float* lsF = (float*)smem;
#pragma unroll
  for (int half = 0; half < 2; ++half) {
    if (wm == half) {
#pragma unroll
      for (int mi = 0; mi < 4; ++mi)
#pragma unroll
        for (int j = 0; j < 4; ++j) {
          int rloc = mi * 16 + lk * 4 + j;
          size_t row = t0 + half * 64 + rloc;
          int b_ = (int)(row >> 15), s = (int)(row & (SPD - 1));
#pragma unroll
          for (int ni = 0; ni < 4; ++ni) {
            int col = bn * 128 + wn * 64 + ni * 16 + lr;
            lsF[rloc * 132 + wn * 64 + ni * 16 + lr] =
                acc[mi][ni][j] + bs[ni] + res[(((size_t)b_ * DIM + col) << 15) + s];
          }
        }
    }
    __syncthreads();
#pragma unroll
    for (int it = 0; it < 8; ++it) {
      int rloc = it * 8 + (tid >> 5);
      int c4 = (tid & 31) * 4;
      f32x4 v = *(f32x4*)(lsF + rloc * 132 + c4);
      *(f32x4*)(O + (t0 + half * 64 + rloc) * N + bn * 128 + c4) = v;
    }
    __syncthreads();
  }
}

// ---------------- fp8 GEMM, BK=64: C[M,N] = A(fp8)[M,K] @ BT(fp8)[N,K] -------
// r13 swizzle f(row)=(row&3)^((row>>2)&3) both sides; r14 hoisted fr.
// EPI 2: +bias, GELU -> fp8 out (fc1), f32 restage
// EPI 3: qkv split output -- bn<6: +bias -> fp8 qk8 (stride 768);
//        bn>=6: +bias -> bf16 v16 (stride 384).
template <int EPI>
__global__ __launch_bounds__(256, 3) void gemm_fp8(
    const unsigned char* __restrict__ A, const unsigned char* __restrict__ BT,
    const float* __restrict__ bias, void* __restrict__ outp,
    void* __restrict__ outp2, int K, int N, int bnCnt) {
  __shared__ char smem[33792];   // 2x16KB dbuf; epilogue restage 33792
  int tid = threadIdx.x;
  int nwg = gridDim.x;
  int cpx = nwg >> 3;
  int swz = ((int)blockIdx.x & 7) * cpx + ((int)blockIdx.x >> 3);
  int bm = swz / bnCnt, bn = swz - bm * bnCnt;
  size_t t0 = (size_t)bm * 128;
  int srow = tid >> 2;                        // 0..63
  int sf = (srow & 3) ^ ((srow >> 2) & 3);    // swizzle key (stage side)
  int scol = ((tid & 3) ^ sf) * 16;           // swizzled 16B source chunk
  const unsigned char* Ab = A + (t0 + srow) * K + scol;
  const unsigned char* Bb = BT + ((size_t)bn * 128 + srow) * K + scol;
  f32x4 acc[4][4];
#pragma unroll
  for (int i = 0; i < 4; ++i)
#pragma unroll
    for (int j = 0; j < 4; ++j) acc[i][j] = (f32x4){0.f, 0.f, 0.f, 0.f};
  int w = tid >> 6, l = tid & 63;
  int wm = w >> 1, wn = w & 1, lr = l & 15, lk = l >> 4;
  const int fr = (lr & 3) ^ ((lr >> 2) & 3);  // == f(row) for ALL MFMA rows

  auto stage = [&](int buf, int kt) {
    char* base = smem + buf * 16384 + tid * 16;
    __builtin_amdgcn_global_load_lds((const void*)(Ab + kt), (void*)(base), 16, 0, 0);
    __builtin_amdgcn_global_load_lds((const void*)(Ab + kt + (size_t)64 * K), (void*)(base + 4096), 16, 0, 0);
    __builtin_amdgcn_global_load_lds((const void*)(Bb + kt), (void*)(base + 8192), 16, 0, 0);
    __builtin_amdgcn_global_load_lds((const void*)(Bb + kt + (size_t)64 * K), (void*)(base + 12288), 16, 0, 0);
  };
  auto compute = [&](int buf) {
    char* baseA = smem + buf * 16384 + (wm * 64 + lr) * 64;
    char* baseB = smem + buf * 16384 + 8192 + (wn * 64 + lr) * 64;
#pragma unroll
    for (int ks = 0; ks < 2; ++ks) {
      int off = ((ks * 2 + (lk >> 1)) ^ fr) * 16 + (lk & 1) * 8;
      long long af[4], bfr[4];
#pragma unroll
      for (int mi = 0; mi < 4; ++mi) af[mi] = *(long long*)(baseA + mi * 1024 + off);
#pragma unroll
      for (int ni = 0; ni < 4; ++ni) bfr[ni] = *(long long*)(baseB + ni * 1024 + off);
#pragma unroll
      for (int mi = 0; mi < 4; ++mi)
#pragma unroll
        for (int ni = 0; ni < 4; ++ni)
          acc[mi][ni] = __builtin_amdgcn_mfma_f32_16x16x32_fp8_fp8(af[mi], bfr[ni], acc[mi][ni], 0, 0, 0);
    }
  };

  int nt = K >> 6;               // BK=64
  stage(0, 0);
  __syncthreads();
  for (int t = 1; t < nt; ++t) {
    stage(t & 1, t * 64);
    compute((t - 1) & 1);
    __syncthreads();
  }
  compute((nt - 1) & 1);

  float bs[4];
#pragma unroll
  for (int ni = 0; ni < 4; ++ni) bs[ni] = bias[bn * 128 + wn * 64 + ni * 16 + lr];

  __syncthreads();                      // done with dbuf LDS
  bool fp8out = (EPI == 2) || (EPI == 3 && bn < 6);
  if (!fp8out) {
    // bf16 out (v cols): stage bf16 C-tile [128][132], coalesced 16B stores
    short* lsC = (short*)smem;
#pragma unroll
    for (int mi = 0; mi < 4; ++mi)
#pragma unroll
      for (int j = 0; j < 4; ++j) {
        int row = wm * 64 + mi * 16 + lk * 4 + j;
#pragma unroll
        for (int ni = 0; ni < 4; ++ni)
          lsC[row * 132 + wn * 64 + ni * 16 + lr] = f2b(acc[mi][ni][j] + bs[ni]);
      }
    __syncthreads();
    short* O = (short*)outp2;
    int cb = (bn - 6) * 128;
#pragma unroll
    for (int it = 0; it < 8; ++it) {
      int row = it * 16 + (tid >> 4);
      int c8 = (tid & 15) * 8;
      short8v v = *(short8v*)(lsC + row * 132 + c8);
      *(short8v*)(O + (t0 + row) * 384 + cb + c8) = v;
    }
  } else {
    // fp8 out via f32 restage (EPI2: +GELU; EPI3 qk: plain)
    float* lsF = (float*)smem;
    unsigned char* O = (unsigned char*)outp;
    int Nst = (EPI == 2) ? N : 768;
#pragma unroll
    for (int h = 0; h < 2; ++h) {
      if (wm == h) {
#pragma unroll
        for (int mi = 0; mi < 4; ++mi)
#pragma unroll
          for (int j = 0; j < 4; ++j) {
            int rloc = mi * 16 + lk * 4 + j;   // 0..63
#pragma unroll
            for (int ni = 0; ni < 4; ++ni)
              lsF[rloc * 132 + wn * 64 + ni * 16 + lr] = acc[mi][ni][j] + bs[ni];
          }
      }
      __syncthreads();
#pragma unroll
      for (int it = 0; it < 2; ++it) {
        int id = it * 256 + tid;
        int row = id >> 3, c16 = (id & 7) * 16;
        const float* p = lsF + row * 132 + c16;
        int4v ov;
#pragma unroll
        for (int q = 0; q < 4; ++q) {
          if constexpr (EPI == 2)
            ov[q] = pk4_fp8(fast_gelu(p[q * 4 + 0]), fast_gelu(p[q * 4 + 1]),
                            fast_gelu(p[q * 4 + 2]), fast_gelu(p[q * 4 + 3]));
          else
            ov[q] = pk4_fp8(p[q * 4 + 0], p[q * 4 + 1], p[q * 4 + 2], p[q * 4 + 3]);
        }
        *(int4v*)(O + (t0 + h * 64 + row) * (size_t)Nst + bn * 128 + c16) = ov;
      }
      __syncthreads();
    }
  }
}

// ---------------- fc2: C = h(fp8)[M,1536] @ fc2T8(fp8)[384,1536]^T ------------
// r17: __launch_bounds__(256,4) caps regs at 128 total; natural use is 132
// (68 VGPR + 64 AGPR, 3 waves/SIMD, occ 28% -- the only GEMM below 4 waves).
// The 4-reg overshoot is epilogue-only (res-pointer chains; K-loop needs
// ~120 < 128), so the allocator remats/spills epilogue values, not the loop.
// Tripwire: FETCH_SIZE blowup = loop spill (r3 signature) -> revert.
__global__ __launch_bounds__(256, 4) void gemm_fp8_ep3(
    const unsigned char* __restrict__ A, const unsigned char* __restrict__ BT,
    const float* __restrict__ bias, const float* __restrict__ res,
    float* __restrict__ O, int bnCnt) {
  __shared__ char smem[33792];
  const int K = 1536, N = 384;
  int tid = threadIdx.x;
  int nwg = gridDim.x;
  int cpx = nwg >> 3;
  int swz = ((int)blockIdx.x & 7) * cpx + ((int)blockIdx.x >> 3);
  int bm = swz / bnCnt, bn = swz - bm * bnCnt;
  size_t t0 = (size_t)bm * 128;
  int srow = tid >> 2;
  int sf = (srow & 3) ^ ((srow >> 2) & 3);
  int scol = ((tid & 3) ^ sf) * 16;
  const unsigned char* Ab = A + (t0 + srow) * K + scol;
  const unsigned char* Bb = BT + ((size_t)bn * 128 + srow) * K + scol;
  f32x4 acc[4][4];
#pragma unroll
  for (int i = 0; i < 4; ++i)
#pragma unroll
    for (int j = 0; j < 4; ++j) acc[i][j] = (f32x4){0.f, 0.f, 0.f, 0.f};
  int w = tid >> 6, l = tid & 63;
  int wm = w >> 1, wn = w & 1, lr = l & 15, lk = l >> 4;
  const int fr = (lr & 3) ^ ((lr >> 2) & 3);

  auto stage = [&](int buf, int kt) {
    char* base = smem + buf * 16384 + tid * 16;
    __builtin_amdgcn_global_load_lds((const void*)(Ab + kt), (void*)(base), 16, 0, 0);
    __builtin_amdgcn_global_load_lds((const void*)(Ab + kt + (size_t)64 * K), (void*)(base + 4096), 16, 0, 0);
    __builtin_amdgcn_global_load_lds((const void*)(Bb + kt), (void*)(base + 8192), 16, 0, 0);
    __builtin_amdgcn_global_load_lds((const void*)(Bb + kt + (size_t)64 * K), (void*)(base + 12288), 16, 0, 0);
  };
  auto compute = [&](int buf) {
    char* baseA = smem + buf * 16384 + (wm * 64 + lr) * 64;
    char* baseB = smem + buf * 16384 + 8192 + (wn * 64 + lr) * 64;
#pragma unroll
    for (int ks = 0; ks < 2; ++ks) {
      int off = ((ks * 2 + (lk >> 1)) ^ fr) * 16 + (lk & 1) * 8;
      long long af[4], bfr[4];
#pragma unroll
      for (int mi = 0; mi < 4; ++mi) af[mi] = *(long long*)(baseA + mi * 1024 + off);
#pragma unroll
      for (int ni = 0; ni < 4; ++ni) bfr[ni] = *(long long*)(baseB + ni * 1024 + off);
#pragma unroll
      for (int mi = 0; mi < 4; ++mi)
#pragma unroll
        for (int ni = 0; ni < 4; ++ni)
          acc[mi][ni] = __builtin_amdgcn_mfma_f32_16x16x32_fp8_fp8(af[mi], bfr[ni], acc[mi][ni], 0, 0, 0);
    }
  };

  const int nt = K >> 6;         // 24
  stage(0, 0);
  __syncthreads();
  for (int t = 1; t < nt; ++t) {
    stage(t & 1, t * 64);
    compute((t - 1) & 1);
    __syncthreads();
  }
  compute((nt - 1) & 1);

  float bs[4];
#pragma unroll
  for (int ni = 0; ni < 4; ++ni) bs[ni] = bias[bn * 128 + wn * 64 + ni * 16 + lr];

  __syncthreads();                     // all waves done with dbuf LDS
  float* lsT = (float*)smem;           // [64 cols][132]
  int bb = (int)(t0 >> 15), s0 = (int)(t0 & (SPD - 1));
  const float* resRow = res + t0 * N + bn * 128 + wn * 64 + lr;   // + rloc*N
#pragma unroll
  for (int half = 0; half < 2; ++half) {
    if (wn == half) {
#pragma unroll
      for (int mi = 0; mi < 4; ++mi)
#pragma unroll
        for (int j = 0; j < 4; ++j) {
          int rloc = wm * 64 + mi * 16 + lk * 4 + j;
          const float* rp = resRow + (size_t)rloc * N;
#pragma unroll
          for (int ni = 0; ni < 4; ++ni)
            lsT[(ni * 16 + lr) * 132 + rloc] = acc[mi][ni][j] + bs[ni] + rp[ni * 16];
        }
    }
    __syncthreads();
    int rloc = tid & 127;
#pragma unroll
    for (int cc = tid >> 7; cc < 64; cc += 2) {
      int col = bn * 128 + half * 64 + cc;
      O[(((size_t)bb * DIM + col) << 15) + s0 + rloc] = lsT[cc * 132 + rloc];
    }
    __syncthreads();
  }
}

// ---------------- K3: windowed attention, QK^T in fp8, one wave/(window,head) --
// r16: q,k read from fp8 qk8 (stride 768) via mfma_f32_16x16x32_fp8_fp8;
// V stays bf16 (v16, stride 384).
__global__ __launch_bounds__(64) void attn_win_mfma(
    const unsigned char* __restrict__ qk8, const short* __restrict__ v16,
    const float* __restrict__ table, short* __restrict__ aout) {
  __shared__ short vT[48 * 72];    // V transposed [d][m], stride 72
  __shared__ short Pls[64 * 72];   // P bf16 [n][m], stride 72; reused for out staging [64][56]
  __shared__ float ltab[343];
  int l = threadIdx.x;
  int wid = blockIdx.x >> 3, head = blockIdx.x & 7;
  int bb = wid >> 9, cube = wid & 511;
  int wd = cube >> 6, wh = (cube >> 3) & 7, ww = cube & 7;
  int sbase = (bb << 15) + ((wd * 4) << 10) + ((wh * 4) << 5) + (ww * 4);

  auto toki = [&](int t) -> int {
    return sbase + ((t >> 4) << 10) + (((t >> 2) & 3) << 5) + (t & 3);
  };

  for (int i = l; i < 343; i += 64) ltab[i] = table[i * 8 + head];

  // stage V transposed: lane l = token m, reads 48 ch, scatters to vT[d][l]
  {
    size_t a = (size_t)toki(l) * 384 + (size_t)head * 48;
#pragma unroll
    for (int c8 = 0; c8 < 6; ++c8) {
      short8v vv = *(const short8v*)(v16 + a + c8 * 8);
#pragma unroll
      for (int u = 0; u < 8; ++u) vT[(c8 * 8 + u) * 72 + l] = vv[u];
    }
  }

  int li = l & 15, lg = l >> 4;

  // Q/K fragments (fp8) direct from global; k-dim zero-padded 48->64
  long long qf[4][2], kf[4][2];
#pragma unroll
  for (int mi = 0; mi < 4; ++mi) {
    size_t aq = (size_t)toki(mi * 16 + li) * 768 + (size_t)head * 48;
    qf[mi][0] = *(const long long*)(qk8 + aq + lg * 8);
    qf[mi][1] = (lg < 2) ? *(const long long*)(qk8 + aq + 32 + lg * 8) : 0LL;
    size_t ak = aq + 384;
    kf[mi][0] = *(const long long*)(qk8 + ak + lg * 8);
    kf[mi][1] = (lg < 2) ? *(const long long*)(qk8 + ak + 32 + lg * 8) : 0LL;
  }

  f32x4 acc[4][4];
#pragma unroll
  for (int i = 0; i < 4; ++i)
#pragma unroll
    for (int j = 0; j < 4; ++j) acc[i][j] = (f32x4){0.f, 0.f, 0.f, 0.f};
  __builtin_amdgcn_s_setprio(1);
#pragma unroll
  for (int ks = 0; ks < 2; ++ks)
#pragma unroll
    for (int mi = 0; mi < 4; ++mi)
#pragma unroll
      for (int ni = 0; ni < 4; ++ni)
        acc[mi][ni] = __builtin_amdgcn_mfma_f32_16x16x32_fp8_fp8(qf[mi][ks], kf[ni][ks], acc[mi][ni], 0, 0, 0);
  __builtin_amdgcn_s_setprio(0);

  __syncthreads();   // ltab + vT staging complete

  // bias + softmax.  C-layout: row n = mi*16 + lg*4 + j, col m = ni*16 + li
  int dh7 = (lg - (li >> 2) + 3) * 7;
  int pwc = li & 3;
  const float scale = 0.14433756729740643f;
#pragma unroll
  for (int mi = 0; mi < 4; ++mi)
#pragma unroll
    for (int ni = 0; ni < 4; ++ni) {
      int dd = (mi - ni + 3) * 49 + dh7;
#pragma unroll
      for (int j = 0; j < 4; ++j)
        acc[mi][ni][j] = acc[mi][ni][j] * scale + ltab[dd + (j - pwc + 3)];
    }

  float inv[4][4];
#pragma unroll
  for (int mi = 0; mi < 4; ++mi)
#pragma unroll
    for (int j = 0; j < 4; ++j) {
      float mx = fmaxf(fmaxf(acc[mi][0][j], acc[mi][1][j]), fmaxf(acc[mi][2][j], acc[mi][3][j]));
      mx = fmaxf(mx, __shfl_xor(mx, 1));
      mx = fmaxf(mx, __shfl_xor(mx, 2));
      mx = fmaxf(mx, __shfl_xor(mx, 4));
      mx = fmaxf(mx, __shfl_xor(mx, 8));
      float s = 0.f;
#pragma unroll
      for (int ni = 0; ni < 4; ++ni) {
        float p = __expf(acc[mi][ni][j] - mx);
        acc[mi][ni][j] = p;
        s += p;
      }
      s += __shfl_xor(s, 1);
      s += __shfl_xor(s, 2);
      s += __shfl_xor(s, 4);
      s += __shfl_xor(s, 8);
      inv[mi][j] = 1.f / s;
    }

  // normalized P -> LDS bf16
#pragma unroll
  for (int mi = 0; mi < 4; ++mi)
#pragma unroll
    for (int ni = 0; ni < 4; ++ni)
#pragma unroll
      for (int j = 0; j < 4; ++j)
        Pls[(mi * 16 + lg * 4 + j) * 72 + ni * 16 + li] = f2b(acc[mi][ni][j] * inv[mi][j]);
  __syncthreads();

  // PV: out[n][d] = P[n][m] @ V[m][d]  (bf16)
  f32x4 o[4][3];
#pragma unroll
  for (int i = 0; i < 4; ++i)
#pragma unroll
    for (int j = 0; j < 3; ++j) o[i][j] = (f32x4){0.f, 0.f, 0.f, 0.f};
#pragma unroll
  for (int ks = 0; ks < 2; ++ks) {
    short8v pa[4], vb[3];
#pragma unroll
    for (int mi = 0; mi < 4; ++mi) pa[mi] = *(short8v*)(Pls + (mi * 16 + li) * 72 + ks * 32 + lg * 8);
#pragma unroll
    for (int ni = 0; ni < 3; ++ni) vb[ni] = *(short8v*)(vT + (ni * 16 + li) * 72 + ks * 32 + lg * 8);
    __builtin_amdgcn_s_setprio(1);
#pragma unroll
    for (int mi = 0; mi < 4; ++mi)
#pragma unroll
      for (int ni = 0; ni < 3; ++ni)
        o[mi][ni] = __builtin_amdgcn_mfma_f32_16x16x32_bf16(pa[mi], vb[ni], o[mi][ni], 0, 0, 0);
    __builtin_amdgcn_s_setprio(0);
  }
  __syncthreads();

  // out bf16 -> LDS [64][56], then coalesced 16B global stores
#pragma unroll
  for (int mi = 0; mi < 4; ++mi)
#pragma unroll
    for (int ni = 0; ni < 3; ++ni)
#pragma unroll
      for (int j = 0; j < 4; ++j)
        Pls[(mi * 16 + lg * 4 + j) * 56 + ni * 16 + li] = f2b(o[mi][ni][j]);
  __syncthreads();
#pragma unroll
  for (int it = 0; it < 6; ++it) {
    int c = it * 64 + l;
    int row = c / 6, part = c - row * 6;
    short8v vv = *(short8v*)(Pls + row * 56 + part * 8);
    *(short8v*)(aout + (size_t)toki(row) * 384 + (size_t)head * 48 + part * 8) = vv;
  }
}

// ---------------- K5: LN2 (token-major fp32 -> FP8) ----------------
__global__ __launch_bounds__(256) void ln2_apply(
    const float* __restrict__ x2, const float* __restrict__ g,
    const float* __restrict__ b, unsigned char* __restrict__ out) {
  int t = (blockIdx.x << 2) + (threadIdx.x >> 6);
  int lane = threadIdx.x & 63;
  const float* row = x2 + (size_t)t * DIM;
  float v[6];
  float sum = 0.f, sq = 0.f;
#pragma unroll
  for (int i = 0; i < 6; ++i) {
    v[i] = row[i * 64 + lane];
    sum += v[i]; sq += v[i] * v[i];
  }
#pragma unroll
  for (int off = 1; off < 64; off <<= 1) { sum += __shfl_xor(sum, off); sq += __shfl_xor(sq, off); }
  float mean = sum * (1.f / 384.f);
  float rstd = rsqrtf(sq * (1.f / 384.f) - mean * mean + 1e-5f);
  unsigned char* orow = out + (size_t)t * DIM;
#pragma unroll
  for (int i = 0; i < 6; ++i) {
    int c = i * 64 + lane;
    orow[c] = f2fp8((v[i] - mean) * rstd * g[c] + b[c]);
  }
}

extern "C" void kernel_launch(void* const* d_in, const int* in_sizes, int n_in,
                              void* d_out, int out_size, void* d_ws, size_t ws_size,
                              hipStream_t stream) {
  (void)in_sizes; (void)n_in; (void)out_size; (void)ws_size;
  const float* x     = (const float*)d_in[0];
  const float* n1g   = (const float*)d_in[1];
  const float* n1b   = (const float*)d_in[2];
  const float* qkvW  = (const float*)d_in[3];
  const float* qkvB  = (const float*)d_in[4];
  const float* tab   = (const float*)d_in[5];
  const float* projW = (const float*)d_in[6];
  const float* projB = (const float*)d_in[7];
  const float* n2g   = (const float*)d_in[8];
  const float* n2b   = (const float*)d_in[9];
  const float* fc1W  = (const float*)d_in[10];
  const float* fc1B  = (const float*)d_in[11];
  const float* fc2W  = (const float*)d_in[12];
  const float* fc2B  = (const float*)d_in[13];

  char* ws = (char*)d_ws;
  unsigned char* qkvT8 = (unsigned char*)(ws);             // 1152*384 fp8
  short* projT = (short*)(ws + 442368);                    //  384*384 bf16
  unsigned char* fc1T8 = (unsigned char*)(ws + 737280);    // 1536*384 fp8
  unsigned char* fc2T8 = (unsigned char*)(ws + 1327104);   // 384*1536 fp8
  // sequenced overlays (lifetimes disjoint):
  unsigned char* xln8   = (unsigned char*)(ws + 3538944);  // 65536*384 fp8 (dead after qkv gemm)
  float*         x2     = (float*)(ws + 3538944);          // 65536*384 fp32 (proj out, after xln8 dead)
  unsigned char* qk8    = (unsigned char*)(ws + 104202240);// 65536*768 fp8 (dead after attn)
  short*         v16    = (short*)(ws + 154533888);        // 65536*384 bf16 (dead after attn)
  unsigned char* h8     = (unsigned char*)(ws + 104202240);// 65536*1536 fp8 (fc1 out, after qk8/v16 dead)
  short*         aoutp  = (short*)(ws + 255197184);        // 65536*384 bf16 (dead after proj)
  unsigned char* xln2_8 = (unsigned char*)(ws + 255197184);// 65536*384 fp8 (ln2 out, after aoutp dead)

  wprep<<<1728, 256, 0, stream>>>(qkvW, projW, fc1W, fc2W, qkvT8, projT, fc1T8, fc2T8);
  ln1_part<<<2048, 256, 0, stream>>>(x, n1g, n1b, xln8);
  gemm_fp8<3><<<4608, 256, 0, stream>>>(xln8, qkvT8, qkvB, (void*)qk8, (void*)v16, 384, 1152, 9);
  attn_win_mfma<<<8192, 64, 0, stream>>>(qk8, v16, tab, aoutp);
  gemm_proj<<<1536, 256, 0, stream>>>(aoutp, projT, projB, x, x2, 384, 384, 3);
  ln2_apply<<<16384, 256, 0, stream>>>(x2, n2g, n2b, xln2_8);
  gemm_fp8<2><<<6144, 256, 0, stream>>>(xln2_8, fc1T8, fc1B, (void*)h8, nullptr, 384, 1536, 12);
  gemm_fp8_ep3<<<1536, 256, 0, stream>>>(h8, fc2T8, fc2B, x2, (float*)d_out, 3);
}

// Round 18
// 419.595 us; speedup vs baseline: 1.0124x; 1.0124x over previous
//
#include <hip/hip_runtime.h>

#define DIM 384
#define SPD 32768   // 32*32*32 spatial per batch

using short8v = __attribute__((ext_vector_type(8))) short;
using f32x4   = __attribute__((ext_vector_type(4))) float;
using int4v   = __attribute__((ext_vector_type(4))) int;
using int2v   = __attribute__((ext_vector_type(2))) int;

__device__ __forceinline__ float b2f(short s) {
  unsigned u = ((unsigned)(unsigned short)s) << 16;
  return __builtin_bit_cast(float, u);
}
__device__ __forceinline__ short f2b(float f) {
  unsigned u = __builtin_bit_cast(unsigned, f);
  u += 0x7FFFu + ((u >> 16) & 1u);   // RNE
  return (short)(u >> 16);
}
__device__ __forceinline__ unsigned char f2fp8(float f) {
  return (unsigned char)(__builtin_amdgcn_cvt_pk_fp8_f32(f, f, 0, false) & 0xff);
}
// pack 4 floats -> 4 fp8 bytes (byte0 = a)
__device__ __forceinline__ int pk4_fp8(float a, float b, float c, float d) {
  int r = 0;
  r = __builtin_amdgcn_cvt_pk_fp8_f32(a, b, r, false);
  r = __builtin_amdgcn_cvt_pk_fp8_f32(c, d, r, true);
  return r;
}
// tanh-form GELU as x*sigmoid(x*(c1 + c2*x^2)); max |err| vs erf-GELU ~3e-4
__device__ __forceinline__ float fast_gelu(float v) {
  float v2 = v * v;
  float wn = v * __builtin_fmaf(-0.0713548162f, v2, -1.5957691216f);
  float e = __expf(wn);
  return v * __builtin_amdgcn_rcpf(1.0f + e);
}

// ---------------- K0: weights fp32 (K,N) -> transposed; qkv/fc1/fc2 -> fp8,
// proj -> bf16 ----------------
__global__ __launch_bounds__(256) void wprep(
    const float* __restrict__ qkv_w, const float* __restrict__ proj_w,
    const float* __restrict__ fc1_w, const float* __restrict__ fc2_w,
    unsigned char* __restrict__ qkvT8, short* __restrict__ projT,
    unsigned char* __restrict__ fc1T8, unsigned char* __restrict__ fc2T8) {
  int blk = blockIdx.x;
  const float* src; short* dst = nullptr; unsigned char* dst8 = nullptr; int K, N;
  if (blk < 432)       {              src = qkv_w;  dst8 = qkvT8; K = 384;  N = 1152; }
  else if (blk < 576)  { blk -= 432;  src = proj_w; dst = projT;  K = 384;  N = 384;  }
  else if (blk < 1152) { blk -= 576;  src = fc1_w;  dst8 = fc1T8; K = 384;  N = 1536; }
  else                 { blk -= 1152; src = fc2_w;  dst8 = fc2T8; K = 1536; N = 384;  }
  int tn = N >> 5;
  int k0 = (blk / tn) << 5, n0 = (blk % tn) << 5;
  __shared__ float tile[32][33];
  int lr = threadIdx.x >> 5, lc = threadIdx.x & 31;
#pragma unroll
  for (int i = 0; i < 4; ++i) {
    int r = i * 8 + lr;
    tile[r][lc] = src[(size_t)(k0 + r) * N + n0 + lc];
  }
  __syncthreads();
#pragma unroll
  for (int i = 0; i < 4; ++i) {
    int r = i * 8 + lr;
    if (dst) dst[(size_t)(n0 + r) * K + k0 + lc] = f2b(tile[lc][r]);
    else     dst8[(size_t)(n0 + r) * K + k0 + lc] = f2fp8(tile[lc][r]);
  }
}

// ---------------- K1: LN1 + (B,C,D,H,W) -> token-major FP8 ----------------
__global__ __launch_bounds__(256) void ln1_part(
    const float* __restrict__ x, const float* __restrict__ g,
    const float* __restrict__ b, unsigned char* __restrict__ xln) {
  __shared__ float tile[32 * 385];   // [s][c], padded row stride
  __shared__ float sg[DIM], sb[DIM];
  int tid = threadIdx.x;
  int t0 = blockIdx.x << 5;
  int bb = t0 >> 15, s0 = t0 & (SPD - 1);
  const float* xb = x + ((size_t)bb * DIM) * SPD + s0;
  for (int i = tid; i < DIM; i += 256) { sg[i] = g[i]; sb[i] = b[i]; }
  for (int i = tid; i < DIM * 32; i += 256) {
    int c = i >> 5, sl = i & 31;
    tile[sl * 385 + c] = xb[(size_t)c * SPD + sl];
  }
  __syncthreads();
  int sl = tid >> 3, j = tid & 7;   // 8 lanes per token
  const float* row = &tile[sl * 385];
  float sum = 0.f, sq = 0.f;
#pragma unroll
  for (int u = 0; u < 48; ++u) { float v = row[j * 48 + u]; sum += v; sq += v * v; }
#pragma unroll
  for (int off = 1; off < 8; off <<= 1) { sum += __shfl_xor(sum, off); sq += __shfl_xor(sq, off); }
  float mean = sum * (1.f / 384.f);
  float rstd = rsqrtf(sq * (1.f / 384.f) - mean * mean + 1e-5f);
  unsigned char* orow = xln + (size_t)(t0 + sl) * DIM + j * 48;
#pragma unroll
  for (int c8 = 0; c8 < 48; c8 += 8) {
    float f[8];
#pragma unroll
    for (int u = 0; u < 8; ++u) {
      int c = j * 48 + c8 + u;
      f[u] = (row[c] - mean) * rstd * sg[c] + sb[c];
    }
    int2v o = { pk4_fp8(f[0], f[1], f[2], f[3]), pk4_fp8(f[4], f[5], f[6], f[7]) };
    *(int2v*)(orow + c8) = o;
  }
}

// ---------------- proj GEMM (bf16, r0-exact): C = aout @ projT^T --------------
__global__ __launch_bounds__(256, 3) void gemm_proj(
    const short* __restrict__ A, const short* __restrict__ BT,
    const float* __restrict__ bias, const float* __restrict__ res,
    float* __restrict__ O, int K, int N, int bnCnt) {
  __shared__ char smem[33792];
  int tid = threadIdx.x;
  int nwg = gridDim.x;
  int cpx = nwg >> 3;
  int swz = ((int)blockIdx.x & 7) * cpx + ((int)blockIdx.x >> 3);
  int bm = swz / bnCnt, bn = swz - bm * bnCnt;
  size_t t0 = (size_t)bm * 128;
  const short* Ab = A + (t0 + (tid >> 2)) * K + ((tid & 3) * 8);
  const short* Bb = BT + ((size_t)bn * 128 + (tid >> 2)) * K + ((tid & 3) * 8);
  f32x4 acc[4][4];
#pragma unroll
  for (int i = 0; i < 4; ++i)
#pragma unroll
    for (int j = 0; j < 4; ++j) acc[i][j] = (f32x4){0.f, 0.f, 0.f, 0.f};
  int w = tid >> 6, l = tid & 63;
  int wm = w >> 1, wn = w & 1, lr = l & 15, lk = l >> 4;

  auto stage = [&](int buf, int kt) {
    char* base = smem + buf * 16384;
    __builtin_amdgcn_global_load_lds((const void*)(Ab + kt), (void*)(base + tid * 16), 16, 0, 0);
    __builtin_amdgcn_global_load_lds((const void*)(Ab + kt + (size_t)64 * K), (void*)(base + 4096 + tid * 16), 16, 0, 0);
    __builtin_amdgcn_global_load_lds((const void*)(Bb + kt), (void*)(base + 8192 + tid * 16), 16, 0, 0);
    __builtin_amdgcn_global_load_lds((const void*)(Bb + kt + (size_t)64 * K), (void*)(base + 12288 + tid * 16), 16, 0, 0);
  };
  auto compute = [&](int buf) {
    short* bA = (short*)smem + buf * 8192 + (wm * 64 + lr) * 32 + lk * 8;
    short* bB = (short*)smem + buf * 8192 + 4096 + (wn * 64 + lr) * 32 + lk * 8;
    short8v af[4], bfr[4];
#pragma unroll
    for (int mi = 0; mi < 4; ++mi) af[mi] = *(short8v*)(bA + mi * 16 * 32);
#pragma unroll
    for (int ni = 0; ni < 4; ++ni) bfr[ni] = *(short8v*)(bB + ni * 16 * 32);
#pragma unroll
    for (int mi = 0; mi < 4; ++mi)
#pragma unroll
      for (int ni = 0; ni < 4; ++ni)
        acc[mi][ni] = __builtin_amdgcn_mfma_f32_16x16x32_bf16(af[mi], bfr[ni], acc[mi][ni], 0, 0, 0);
  };

  int nt = K >> 5;
  stage(0, 0);
  __syncthreads();
  for (int t = 1; t < nt; ++t) {
    stage(t & 1, t * 32);
    compute((t - 1) & 1);
    __syncthreads();
  }
  compute((nt - 1) & 1);

  float bs[4];
#pragma unroll
  for (int ni = 0; ni < 4; ++ni) bs[ni] = bias[bn * 128 + wn * 64 + ni * 16 + lr];

  __syncthreads();
  float* lsF = (float*)smem;
#pragma unroll
  for (int half = 0; half < 2; ++half) {
    if (wm == half) {
#pragma unroll
      for (int mi = 0; mi < 4; ++mi)
#pragma unroll
        for (int j = 0; j < 4; ++j) {
          int rloc = mi * 16 + lk * 4 + j;
          size_t row = t0 + half * 64 + rloc;
          int b_ = (int)(row >> 15), s = (int)(row & (SPD - 1));
#pragma unroll
          for (int ni = 0; ni < 4; ++ni) {
            int col = bn * 128 + wn * 64 + ni * 16 + lr;
            lsF[rloc * 132 + wn * 64 + ni * 16 + lr] =
                acc[mi][ni][j] + bs[ni] + res[(((size_t)b_ * DIM + col) << 15) + s];
          }
        }
    }
    __syncthreads();
#pragma unroll
    for (int it = 0; it < 8; ++it) {
      int rloc = it * 8 + (tid >> 5);
      int c4 = (tid & 31) * 4;
      f32x4 v = *(f32x4*)(lsF + rloc * 132 + c4);
      *(f32x4*)(O + (t0 + half * 64 + rloc) * N + bn * 128 + c4) = v;
    }
    __syncthreads();
  }
}

// ---------------- fp8 GEMM, BK=64: C[M,N] = A(fp8)[M,K] @ BT(fp8)[N,K] -------
// r13 swizzle f(row)=(row&3)^((row>>2)&3) both sides; r14 hoisted fr.
// EPI 2: +bias, GELU -> fp8 out (fc1), f32 restage
// EPI 3: qkv split output -- bn<6: +bias -> fp8 qk8 (stride 768);
//        bn>=6: +bias -> bf16 v16 (stride 384).
template <int EPI>
__global__ __launch_bounds__(256, 3) void gemm_fp8(
    const unsigned char* __restrict__ A, const unsigned char* __restrict__ BT,
    const float* __restrict__ bias, void* __restrict__ outp,
    void* __restrict__ outp2, int K, int N, int bnCnt) {
  __shared__ char smem[33792];   // 2x16KB dbuf; epilogue restage 33792
  int tid = threadIdx.x;
  int nwg = gridDim.x;
  int cpx = nwg >> 3;
  int swz = ((int)blockIdx.x & 7) * cpx + ((int)blockIdx.x >> 3);
  int bm = swz / bnCnt, bn = swz - bm * bnCnt;
  size_t t0 = (size_t)bm * 128;
  int srow = tid >> 2;                        // 0..63
  int sf = (srow & 3) ^ ((srow >> 2) & 3);    // swizzle key (stage side)
  int scol = ((tid & 3) ^ sf) * 16;           // swizzled 16B source chunk
  const unsigned char* Ab = A + (t0 + srow) * K + scol;
  const unsigned char* Bb = BT + ((size_t)bn * 128 + srow) * K + scol;
  f32x4 acc[4][4];
#pragma unroll
  for (int i = 0; i < 4; ++i)
#pragma unroll
    for (int j = 0; j < 4; ++j) acc[i][j] = (f32x4){0.f, 0.f, 0.f, 0.f};
  int w = tid >> 6, l = tid & 63;
  int wm = w >> 1, wn = w & 1, lr = l & 15, lk = l >> 4;
  const int fr = (lr & 3) ^ ((lr >> 2) & 3);  // == f(row) for ALL MFMA rows

  auto stage = [&](int buf, int kt) {
    char* base = smem + buf * 16384 + tid * 16;
    __builtin_amdgcn_global_load_lds((const void*)(Ab + kt), (void*)(base), 16, 0, 0);
    __builtin_amdgcn_global_load_lds((const void*)(Ab + kt + (size_t)64 * K), (void*)(base + 4096), 16, 0, 0);
    __builtin_amdgcn_global_load_lds((const void*)(Bb + kt), (void*)(base + 8192), 16, 0, 0);
    __builtin_amdgcn_global_load_lds((const void*)(Bb + kt + (size_t)64 * K), (void*)(base + 12288), 16, 0, 0);
  };
  auto compute = [&](int buf) {
    char* baseA = smem + buf * 16384 + (wm * 64 + lr) * 64;
    char* baseB = smem + buf * 16384 + 8192 + (wn * 64 + lr) * 64;
#pragma unroll
    for (int ks = 0; ks < 2; ++ks) {
      int off = ((ks * 2 + (lk >> 1)) ^ fr) * 16 + (lk & 1) * 8;
      long long af[4], bfr[4];
#pragma unroll
      for (int mi = 0; mi < 4; ++mi) af[mi] = *(long long*)(baseA + mi * 1024 + off);
#pragma unroll
      for (int ni = 0; ni < 4; ++ni) bfr[ni] = *(long long*)(baseB + ni * 1024 + off);
#pragma unroll
      for (int mi = 0; mi < 4; ++mi)
#pragma unroll
        for (int ni = 0; ni < 4; ++ni)
          acc[mi][ni] = __builtin_amdgcn_mfma_f32_16x16x32_fp8_fp8(af[mi], bfr[ni], acc[mi][ni], 0, 0, 0);
    }
  };

  int nt = K >> 6;               // BK=64
  stage(0, 0);
  __syncthreads();
  for (int t = 1; t < nt; ++t) {
    stage(t & 1, t * 64);
    compute((t - 1) & 1);
    __syncthreads();
  }
  compute((nt - 1) & 1);

  float bs[4];
#pragma unroll
  for (int ni = 0; ni < 4; ++ni) bs[ni] = bias[bn * 128 + wn * 64 + ni * 16 + lr];

  __syncthreads();                      // done with dbuf LDS
  bool fp8out = (EPI == 2) || (EPI == 3 && bn < 6);
  if (!fp8out) {
    // bf16 out (v cols): stage bf16 C-tile [128][132], coalesced 16B stores
    short* lsC = (short*)smem;
#pragma unroll
    for (int mi = 0; mi < 4; ++mi)
#pragma unroll
      for (int j = 0; j < 4; ++j) {
        int row = wm * 64 + mi * 16 + lk * 4 + j;
#pragma unroll
        for (int ni = 0; ni < 4; ++ni)
          lsC[row * 132 + wn * 64 + ni * 16 + lr] = f2b(acc[mi][ni][j] + bs[ni]);
      }
    __syncthreads();
    short* O = (short*)outp2;
    int cb = (bn - 6) * 128;
#pragma unroll
    for (int it = 0; it < 8; ++it) {
      int row = it * 16 + (tid >> 4);
      int c8 = (tid & 15) * 8;
      short8v v = *(short8v*)(lsC + row * 132 + c8);
      *(short8v*)(O + (t0 + row) * 384 + cb + c8) = v;
    }
  } else {
    // fp8 out via f32 restage (EPI2: +GELU; EPI3 qk: plain)
    float* lsF = (float*)smem;
    unsigned char* O = (unsigned char*)outp;
    int Nst = (EPI == 2) ? N : 768;
#pragma unroll
    for (int h = 0; h < 2; ++h) {
      if (wm == h) {
#pragma unroll
        for (int mi = 0; mi < 4; ++mi)
#pragma unroll
          for (int j = 0; j < 4; ++j) {
            int rloc = mi * 16 + lk * 4 + j;   // 0..63
#pragma unroll
            for (int ni = 0; ni < 4; ++ni)
              lsF[rloc * 132 + wn * 64 + ni * 16 + lr] = acc[mi][ni][j] + bs[ni];
          }
      }
      __syncthreads();
#pragma unroll
      for (int it = 0; it < 2; ++it) {
        int id = it * 256 + tid;
        int row = id >> 3, c16 = (id & 7) * 16;
        const float* p = lsF + row * 132 + c16;
        int4v ov;
#pragma unroll
        for (int q = 0; q < 4; ++q) {
          if constexpr (EPI == 2)
            ov[q] = pk4_fp8(fast_gelu(p[q * 4 + 0]), fast_gelu(p[q * 4 + 1]),
                            fast_gelu(p[q * 4 + 2]), fast_gelu(p[q * 4 + 3]));
          else
            ov[q] = pk4_fp8(p[q * 4 + 0], p[q * 4 + 1], p[q * 4 + 2], p[q * 4 + 3]);
        }
        *(int4v*)(O + (t0 + h * 64 + row) * (size_t)Nst + bn * 128 + c16) = ov;
      }
      __syncthreads();
    }
  }
}

// ---------------- fc2: C = h(fp8)[M,1536] @ fc2T8(fp8)[384,1536]^T ------------
// r18: reverted to (256,3) -- r17's (256,4) cap caused epilogue spill
// (WRITE_SIZE +6MB) and only reached occ 30.7%, net regression.
__global__ __launch_bounds__(256, 3) void gemm_fp8_ep3(
    const unsigned char* __restrict__ A, const unsigned char* __restrict__ BT,
    const float* __restrict__ bias, const float* __restrict__ res,
    float* __restrict__ O, int bnCnt) {
  __shared__ char smem[33792];
  const int K = 1536, N = 384;
  int tid = threadIdx.x;
  int nwg = gridDim.x;
  int cpx = nwg >> 3;
  int swz = ((int)blockIdx.x & 7) * cpx + ((int)blockIdx.x >> 3);
  int bm = swz / bnCnt, bn = swz - bm * bnCnt;
  size_t t0 = (size_t)bm * 128;
  int srow = tid >> 2;
  int sf = (srow & 3) ^ ((srow >> 2) & 3);
  int scol = ((tid & 3) ^ sf) * 16;
  const unsigned char* Ab = A + (t0 + srow) * K + scol;
  const unsigned char* Bb = BT + ((size_t)bn * 128 + srow) * K + scol;
  f32x4 acc[4][4];
#pragma unroll
  for (int i = 0; i < 4; ++i)
#pragma unroll
    for (int j = 0; j < 4; ++j) acc[i][j] = (f32x4){0.f, 0.f, 0.f, 0.f};
  int w = tid >> 6, l = tid & 63;
  int wm = w >> 1, wn = w & 1, lr = l & 15, lk = l >> 4;
  const int fr = (lr & 3) ^ ((lr >> 2) & 3);

  auto stage = [&](int buf, int kt) {
    char* base = smem + buf * 16384 + tid * 16;
    __builtin_amdgcn_global_load_lds((const void*)(Ab + kt), (void*)(base), 16, 0, 0);
    __builtin_amdgcn_global_load_lds((const void*)(Ab + kt + (size_t)64 * K), (void*)(base + 4096), 16, 0, 0);
    __builtin_amdgcn_global_load_lds((const void*)(Bb + kt), (void*)(base + 8192), 16, 0, 0);
    __builtin_amdgcn_global_load_lds((const void*)(Bb + kt + (size_t)64 * K), (void*)(base + 12288), 16, 0, 0);
  };
  auto compute = [&](int buf) {
    char* baseA = smem + buf * 16384 + (wm * 64 + lr) * 64;
    char* baseB = smem + buf * 16384 + 8192 + (wn * 64 + lr) * 64;
#pragma unroll
    for (int ks = 0; ks < 2; ++ks) {
      int off = ((ks * 2 + (lk >> 1)) ^ fr) * 16 + (lk & 1) * 8;
      long long af[4], bfr[4];
#pragma unroll
      for (int mi = 0; mi < 4; ++mi) af[mi] = *(long long*)(baseA + mi * 1024 + off);
#pragma unroll
      for (int ni = 0; ni < 4; ++ni) bfr[ni] = *(long long*)(baseB + ni * 1024 + off);
#pragma unroll
      for (int mi = 0; mi < 4; ++mi)
#pragma unroll
        for (int ni = 0; ni < 4; ++ni)
          acc[mi][ni] = __builtin_amdgcn_mfma_f32_16x16x32_fp8_fp8(af[mi], bfr[ni], acc[mi][ni], 0, 0, 0);
    }
  };

  const int nt = K >> 6;         // 24
  stage(0, 0);
  __syncthreads();
  for (int t = 1; t < nt; ++t) {
    stage(t & 1, t * 64);
    compute((t - 1) & 1);
    __syncthreads();
  }
  compute((nt - 1) & 1);

  float bs[4];
#pragma unroll
  for (int ni = 0; ni < 4; ++ni) bs[ni] = bias[bn * 128 + wn * 64 + ni * 16 + lr];

  __syncthreads();                     // all waves done with dbuf LDS
  float* lsT = (float*)smem;           // [64 cols][132]
  int bb = (int)(t0 >> 15), s0 = (int)(t0 & (SPD - 1));
  const float* resRow = res + t0 * N + bn * 128 + wn * 64 + lr;   // + rloc*N
#pragma unroll
  for (int half = 0; half < 2; ++half) {
    if (wn == half) {
#pragma unroll
      for (int mi = 0; mi < 4; ++mi)
#pragma unroll
        for (int j = 0; j < 4; ++j) {
          int rloc = wm * 64 + mi * 16 + lk * 4 + j;
          const float* rp = resRow + (size_t)rloc * N;
#pragma unroll
          for (int ni = 0; ni < 4; ++ni)
            lsT[(ni * 16 + lr) * 132 + rloc] = acc[mi][ni][j] + bs[ni] + rp[ni * 16];
        }
    }
    __syncthreads();
    int rloc = tid & 127;
#pragma unroll
    for (int cc = tid >> 7; cc < 64; cc += 2) {
      int col = bn * 128 + half * 64 + cc;
      O[(((size_t)bb * DIM + col) << 15) + s0 + rloc] = lsT[cc * 132 + rloc];
    }
    __syncthreads();
  }
}

// ---------------- K3: windowed attention, QK^T in fp8, one wave/(window,head) --
// r16: q,k read from fp8 qk8 (stride 768) via mfma_f32_16x16x32_fp8_fp8;
// V stays bf16 (v16, stride 384).
__global__ __launch_bounds__(64) void attn_win_mfma(
    const unsigned char* __restrict__ qk8, const short* __restrict__ v16,
    const float* __restrict__ table, short* __restrict__ aout) {
  __shared__ short vT[48 * 72];    // V transposed [d][m], stride 72
  __shared__ short Pls[64 * 72];   // P bf16 [n][m], stride 72; reused for out staging [64][56]
  __shared__ float ltab[343];
  int l = threadIdx.x;
  int wid = blockIdx.x >> 3, head = blockIdx.x & 7;
  int bb = wid >> 9, cube = wid & 511;
  int wd = cube >> 6, wh = (cube >> 3) & 7, ww = cube & 7;
  int sbase = (bb << 15) + ((wd * 4) << 10) + ((wh * 4) << 5) + (ww * 4);

  auto toki = [&](int t) -> int {
    return sbase + ((t >> 4) << 10) + (((t >> 2) & 3) << 5) + (t & 3);
  };

  for (int i = l; i < 343; i += 64) ltab[i] = table[i * 8 + head];

  // stage V transposed: lane l = token m, reads 48 ch, scatters to vT[d][l]
  {
    size_t a = (size_t)toki(l) * 384 + (size_t)head * 48;
#pragma unroll
    for (int c8 = 0; c8 < 6; ++c8) {
      short8v vv = *(const short8v*)(v16 + a + c8 * 8);
#pragma unroll
      for (int u = 0; u < 8; ++u) vT[(c8 * 8 + u) * 72 + l] = vv[u];
    }
  }

  int li = l & 15, lg = l >> 4;

  // Q/K fragments (fp8) direct from global; k-dim zero-padded 48->64
  long long qf[4][2], kf[4][2];
#pragma unroll
  for (int mi = 0; mi < 4; ++mi) {
    size_t aq = (size_t)toki(mi * 16 + li) * 768 + (size_t)head * 48;
    qf[mi][0] = *(const long long*)(qk8 + aq + lg * 8);
    qf[mi][1] = (lg < 2) ? *(const long long*)(qk8 + aq + 32 + lg * 8) : 0LL;
    size_t ak = aq + 384;
    kf[mi][0] = *(const long long*)(qk8 + ak + lg * 8);
    kf[mi][1] = (lg < 2) ? *(const long long*)(qk8 + ak + 32 + lg * 8) : 0LL;
  }

  f32x4 acc[4][4];
#pragma unroll
  for (int i = 0; i < 4; ++i)
#pragma unroll
    for (int j = 0; j < 4; ++j) acc[i][j] = (f32x4){0.f, 0.f, 0.f, 0.f};
  __builtin_amdgcn_s_setprio(1);
#pragma unroll
  for (int ks = 0; ks < 2; ++ks)
#pragma unroll
    for (int mi = 0; mi < 4; ++mi)
#pragma unroll
      for (int ni = 0; ni < 4; ++ni)
        acc[mi][ni] = __builtin_amdgcn_mfma_f32_16x16x32_fp8_fp8(qf[mi][ks], kf[ni][ks], acc[mi][ni], 0, 0, 0);
  __builtin_amdgcn_s_setprio(0);

  __syncthreads();   // ltab + vT staging complete

  // bias + softmax.  C-layout: row n = mi*16 + lg*4 + j, col m = ni*16 + li
  int dh7 = (lg - (li >> 2) + 3) * 7;
  int pwc = li & 3;
  const float scale = 0.14433756729740643f;
#pragma unroll
  for (int mi = 0; mi < 4; ++mi)
#pragma unroll
    for (int ni = 0; ni < 4; ++ni) {
      int dd = (mi - ni + 3) * 49 + dh7;
#pragma unroll
      for (int j = 0; j < 4; ++j)
        acc[mi][ni][j] = acc[mi][ni][j] * scale + ltab[dd + (j - pwc + 3)];
    }

  float inv[4][4];
#pragma unroll
  for (int mi = 0; mi < 4; ++mi)
#pragma unroll
    for (int j = 0; j < 4; ++j) {
      float mx = fmaxf(fmaxf(acc[mi][0][j], acc[mi][1][j]), fmaxf(acc[mi][2][j], acc[mi][3][j]));
      mx = fmaxf(mx, __shfl_xor(mx, 1));
      mx = fmaxf(mx, __shfl_xor(mx, 2));
      mx = fmaxf(mx, __shfl_xor(mx, 4));
      mx = fmaxf(mx, __shfl_xor(mx, 8));
      float s = 0.f;
#pragma unroll
      for (int ni = 0; ni < 4; ++ni) {
        float p = __expf(acc[mi][ni][j] - mx);
        acc[mi][ni][j] = p;
        s += p;
      }
      s += __shfl_xor(s, 1);
      s += __shfl_xor(s, 2);
      s += __shfl_xor(s, 4);
      s += __shfl_xor(s, 8);
      inv[mi][j] = 1.f / s;
    }

  // normalized P -> LDS bf16
#pragma unroll
  for (int mi = 0; mi < 4; ++mi)
#pragma unroll
    for (int ni = 0; ni < 4; ++ni)
#pragma unroll
      for (int j = 0; j < 4; ++j)
        Pls[(mi * 16 + lg * 4 + j) * 72 + ni * 16 + li] = f2b(acc[mi][ni][j] * inv[mi][j]);
  __syncthreads();

  // PV: out[n][d] = P[n][m] @ V[m][d]  (bf16)
  f32x4 o[4][3];
#pragma unroll
  for (int i = 0; i < 4; ++i)
#pragma unroll
    for (int j = 0; j < 3; ++j) o[i][j] = (f32x4){0.f, 0.f, 0.f, 0.f};
#pragma unroll
  for (int ks = 0; ks < 2; ++ks) {
    short8v pa[4], vb[3];
#pragma unroll
    for (int mi = 0; mi < 4; ++mi) pa[mi] = *(short8v*)(Pls + (mi * 16 + li) * 72 + ks * 32 + lg * 8);
#pragma unroll
    for (int ni = 0; ni < 3; ++ni) vb[ni] = *(short8v*)(vT + (ni * 16 + li) * 72 + ks * 32 + lg * 8);
    __builtin_amdgcn_s_setprio(1);
#pragma unroll
    for (int mi = 0; mi < 4; ++mi)
#pragma unroll
      for (int ni = 0; ni < 3; ++ni)
        o[mi][ni] = __builtin_amdgcn_mfma_f32_16x16x32_bf16(pa[mi], vb[ni], o[mi][ni], 0, 0, 0);
    __builtin_amdgcn_s_setprio(0);
  }
  __syncthreads();

  // out bf16 -> LDS [64][56], then coalesced 16B global stores
#pragma unroll
  for (int mi = 0; mi < 4; ++mi)
#pragma unroll
    for (int ni = 0; ni < 3; ++ni)
#pragma unroll
      for (int j = 0; j < 4; ++j)
        Pls[(mi * 16 + lg * 4 + j) * 56 + ni * 16 + li] = f2b(o[mi][ni][j]);
  __syncthreads();
#pragma unroll
  for (int it = 0; it < 6; ++it) {
    int c = it * 64 + l;
    int row = c / 6, part = c - row * 6;
    short8v vv = *(short8v*)(Pls + row * 56 + part * 8);
    *(short8v*)(aout + (size_t)toki(row) * 384 + (size_t)head * 48 + part * 8) = vv;
  }
}

// ---------------- K5: LN2 (token-major fp32 -> FP8) ----------------
__global__ __launch_bounds__(256) void ln2_apply(
    const float* __restrict__ x2, const float* __restrict__ g,
    const float* __restrict__ b, unsigned char* __restrict__ out) {
  int t = (blockIdx.x << 2) + (threadIdx.x >> 6);
  int lane = threadIdx.x & 63;
  const float* row = x2 + (size_t)t * DIM;
  float v[6];
  float sum = 0.f, sq = 0.f;
#pragma unroll
  for (int i = 0; i < 6; ++i) {
    v[i] = row[i * 64 + lane];
    sum += v[i]; sq += v[i] * v[i];
  }
#pragma unroll
  for (int off = 1; off < 64; off <<= 1) { sum += __shfl_xor(sum, off); sq += __shfl_xor(sq, off); }
  float mean = sum * (1.f / 384.f);
  float rstd = rsqrtf(sq * (1.f / 384.f) - mean * mean + 1e-5f);
  unsigned char* orow = out + (size_t)t * DIM;
#pragma unroll
  for (int i = 0; i < 6; ++i) {
    int c = i * 64 + lane;
    orow[c] = f2fp8((v[i] - mean) * rstd * g[c] + b[c]);
  }
}

extern "C" void kernel_launch(void* const* d_in, const int* in_sizes, int n_in,
                              void* d_out, int out_size, void* d_ws, size_t ws_size,
                              hipStream_t stream) {
  (void)in_sizes; (void)n_in; (void)out_size; (void)ws_size;
  const float* x     = (const float*)d_in[0];
  const float* n1g   = (const float*)d_in[1];
  const float* n1b   = (const float*)d_in[2];
  const float* qkvW  = (const float*)d_in[3];
  const float* qkvB  = (const float*)d_in[4];
  const float* tab   = (const float*)d_in[5];
  const float* projW = (const float*)d_in[6];
  const float* projB = (const float*)d_in[7];
  const float* n2g   = (const float*)d_in[8];
  const float* n2b   = (const float*)d_in[9];
  const float* fc1W  = (const float*)d_in[10];
  const float* fc1B  = (const float*)d_in[11];
  const float* fc2W  = (const float*)d_in[12];
  const float* fc2B  = (const float*)d_in[13];

  char* ws = (char*)d_ws;
  unsigned char* qkvT8 = (unsigned char*)(ws);             // 1152*384 fp8
  short* projT = (short*)(ws + 442368);                    //  384*384 bf16
  unsigned char* fc1T8 = (unsigned char*)(ws + 737280);    // 1536*384 fp8
  unsigned char* fc2T8 = (unsigned char*)(ws + 1327104);   // 384*1536 fp8
  // sequenced overlays (lifetimes disjoint):
  unsigned char* xln8   = (unsigned char*)(ws + 3538944);  // 65536*384 fp8 (dead after qkv gemm)
  float*         x2     = (float*)(ws + 3538944);          // 65536*384 fp32 (proj out, after xln8 dead)
  unsigned char* qk8    = (unsigned char*)(ws + 104202240);// 65536*768 fp8 (dead after attn)
  short*         v16    = (short*)(ws + 154533888);        // 65536*384 bf16 (dead after attn)
  unsigned char* h8     = (unsigned char*)(ws + 104202240);// 65536*1536 fp8 (fc1 out, after qk8/v16 dead)
  short*         aoutp  = (short*)(ws + 255197184);        // 65536*384 bf16 (dead after proj)
  unsigned char* xln2_8 = (unsigned char*)(ws + 255197184);// 65536*384 fp8 (ln2 out, after aoutp dead)

  wprep<<<1728, 256, 0, stream>>>(qkvW, projW, fc1W, fc2W, qkvT8, projT, fc1T8, fc2T8);
  ln1_part<<<2048, 256, 0, stream>>>(x, n1g, n1b, xln8);
  gemm_fp8<3><<<4608, 256, 0, stream>>>(xln8, qkvT8, qkvB, (void*)qk8, (void*)v16, 384, 1152, 9);
  attn_win_mfma<<<8192, 64, 0, stream>>>(qk8, v16, tab, aoutp);
  gemm_proj<<<1536, 256, 0, stream>>>(aoutp, projT, projB, x, x2, 384, 384, 3);
  ln2_apply<<<16384, 256, 0, stream>>>(x2, n2g, n2b, xln2_8);
  gemm_fp8<2><<<6144, 256, 0, stream>>>(xln2_8, fc1T8, fc1B, (void*)h8, nullptr, 384, 1536, 12);
  gemm_fp8_ep3<<<1536, 256, 0, stream>>>(h8, fc2T8, fc2B, x2, (float*)d_out, 3);
}